// Round 4
// baseline (1245.412 us; speedup 1.0000x reference)
//
#include <hip/hip_runtime.h>

typedef unsigned int uint;
typedef unsigned long long ull;

#define USER_NUM   100000
#define ITEM_NUM   50000
#define N_NODES    (USER_NUM + ITEM_NUM)
#define NNZ        4800000
#define EMB        64
#define EPS_F      0.2f
#define NORM_EPS_F 1e-12f

// buckets of 256 rows
#define RB_SHIFT   8
#define RB         256
#define NB         ((N_NODES + RB - 1) / RB)     // 586
#define CAP        9216                           // mean 8191, std ~90 -> +11 sigma
#define BINA_CHUNK 8192
#define BINA_GRID  ((NNZ + BINA_CHUNK - 1) / BINA_CHUNK)  // 586

// column chunking for spmm L2 locality: 32768 rows * 128 B = 4 MB = one XCD L2
#define CSHIFT     15
#define NCHUNK     5                              // ceil(150000 / 32768)
#define NKEY       2048                           // 256 rows * 8 chunk slots
#define RPW        19                             // rows per wave
#define SPMM_BLOCKS 2048                          // 8 blocks/CU, all co-resident

// ---------------- bf16 helpers ----------------
__device__ inline float bflo(uint u) { return __uint_as_float(u << 16); }
__device__ inline float bfhi(uint u) { return __uint_as_float(u & 0xffff0000u); }
__device__ inline uint f2bf(float f) {                 // RNE round to bf16
    uint u = __float_as_uint(f);
    return (u + 0x7fffu + ((u >> 16) & 1u)) >> 16;
}
__device__ inline uint pack2(float a, float b) { return f2bf(a) | (f2bf(b) << 16); }

// ---------------- CSR build ----------------

__global__ void init_gcursor(int* __restrict__ g) {
    int b = blockIdx.x * blockDim.x + threadIdx.x;
    if (b < NB) g[b] = b * CAP;
}

// Phase A: block-level LDS counting sort by bucket; bid array for copy-out.
// Sequential copy-out -> coalesced full-line global writes.
__global__ __launch_bounds__(1024) void binA_kernel(const int* __restrict__ rows,
                                                    const int* __restrict__ cols,
                                                    const float* __restrict__ vals,
                                                    int* __restrict__ gcursor,
                                                    int2* __restrict__ staging) {
    __shared__ int2 data[BINA_CHUNK];            // 64 KB
    __shared__ unsigned short bid[BINA_CHUNK];   // 16 KB
    __shared__ int hist[NB];
    __shared__ int rstart[NB + 1];
    __shared__ int gbase[NB];
    __shared__ int lcur[NB];
    __shared__ int wsum[16];
    int t = threadIdx.x;
    int cbeg = blockIdx.x * BINA_CHUNK;
    int cend = min(cbeg + BINA_CHUNK, NNZ);
    int total = cend - cbeg;

    int r[8];
    if (t < NB) hist[t] = 0;
    __syncthreads();
#pragma unroll
    for (int k = 0; k < 8; ++k) {
        int i = cbeg + (k << 10) + t;
        r[k] = (i < cend) ? rows[i] : -1;
        if (r[k] >= 0) atomicAdd(&hist[r[k] >> RB_SHIFT], 1);
    }
    __syncthreads();

    // 2-barrier hierarchical shfl scan of hist -> exclusive run starts
    int v = (t < NB) ? hist[t] : 0;
    int sc = v;
#pragma unroll
    for (int off = 1; off < 64; off <<= 1) {
        int u = __shfl_up(sc, off, 64);
        if ((t & 63) >= off) sc += u;
    }
    if ((t & 63) == 63) wsum[t >> 6] = sc;
    __syncthreads();
    if (t < 64) {
        int ws = (t < 16) ? wsum[t] : 0;
#pragma unroll
        for (int off = 1; off < 16; off <<= 1) {
            int u = __shfl_up(ws, off, 64);
            if (t >= off) ws += u;
        }
        if (t < 16) wsum[t] = ws;
    }
    __syncthreads();
    int wid = t >> 6;
    int excl = sc - v + ((wid > 0) ? wsum[wid - 1] : 0);
    if (t <= NB) rstart[t] = excl;            // rstart[NB] == total
    if (t < NB) {
        gbase[t] = atomicAdd(&gcursor[t], hist[t]);   // one global atomic per bucket
        lcur[t] = 0;
    }
    __syncthreads();

    // sort into LDS by bucket, recording bucket id per slot
#pragma unroll
    for (int k = 0; k < 8; ++k) {
        if (r[k] >= 0) {
            int i = cbeg + (k << 10) + t;
            int b = r[k] >> RB_SHIFT;
            int pos = rstart[b] + atomicAdd(&lcur[b], 1);
            data[pos] = make_int2(((r[k] & (RB - 1)) << 18) | cols[i],
                                  __float_as_int(vals[i]));
            bid[pos] = (unsigned short)b;
        }
    }
    __syncthreads();

    // sequential copy-out: consecutive threads -> consecutive global addresses
    for (int i = t; i < total; i += 1024) {
        int b = bid[i];
        staging[(long)gbase[b] + (i - rstart[b])] = data[i];
    }
}

// exclusive scan of bucket counts -> bucket_base; sentinel row_ptr[N_NODES]
__global__ __launch_bounds__(1024) void bscan_kernel(const int* __restrict__ gcursor,
                                                     int* __restrict__ bucket_base,
                                                     int* __restrict__ row_ptr) {
    __shared__ int wsum[16];
    int t = threadIdx.x;
    int c = (t < NB) ? (gcursor[t] - t * CAP) : 0;
    int sc = c;
#pragma unroll
    for (int off = 1; off < 64; off <<= 1) {
        int u = __shfl_up(sc, off, 64);
        if ((t & 63) >= off) sc += u;
    }
    if ((t & 63) == 63) wsum[t >> 6] = sc;
    __syncthreads();
    if (t < 64) {
        int ws = (t < 16) ? wsum[t] : 0;
#pragma unroll
        for (int off = 1; off < 16; off <<= 1) {
            int u = __shfl_up(ws, off, 64);
            if (t >= off) ws += u;
        }
        if (t < 16) wsum[t] = ws;
    }
    __syncthreads();
    int wid = t >> 6;
    int excl = sc - c + ((wid > 0) ? wsum[wid - 1] : 0);
    if (t < NB) bucket_base[t] = excl;
    if (t == 0) row_ptr[N_NODES] = NNZ;
}

// Phase B: one 1024-thread block per 256-row bucket. Counting sort by key
// (row_local<<3)|col_chunk == (e.x >> 15): edges land grouped by row AND,
// within each row, ordered by column chunk -- this is what enables the
// phased spmm's L2-resident gathers. Sequential copy-out keeps line-dense
// global writes.
__global__ __launch_bounds__(1024) void binB_kernel(const int* __restrict__ gcursor,
                                                    const int* __restrict__ bucket_base,
                                                    const int2* __restrict__ staging,
                                                    int2* __restrict__ edges,
                                                    int* __restrict__ row_ptr) {
    __shared__ int2 sorted[CAP];      // 72 KB
    __shared__ int s[NKEY];           // 8 KB
    __shared__ int cur[NKEY];         // 8 KB
    __shared__ int wsum[16];
    int b = blockIdx.x;
    int t = threadIdx.x;
    int cnt = gcursor[b] - b * CAP;
    long sbase = (long)b * CAP;
    int base = bucket_base[b];

    s[t] = 0;
    s[t + 1024] = 0;
    __syncthreads();
    // pass 1: histogram by (row_local, chunk) key
    for (int i = t; i < cnt; i += 1024)
        atomicAdd(&s[((unsigned)staging[sbase + i].x) >> 15], 1);
    __syncthreads();

    // scan 2048 keys: pair-per-thread + hierarchical shfl scan
    int v0 = s[2 * t], v1 = s[2 * t + 1];
    int pv = v0 + v1;
    int sc = pv;
#pragma unroll
    for (int off = 1; off < 64; off <<= 1) {
        int u = __shfl_up(sc, off, 64);
        if ((t & 63) >= off) sc += u;
    }
    if ((t & 63) == 63) wsum[t >> 6] = sc;
    __syncthreads();
    if (t < 64) {
        int ws = (t < 16) ? wsum[t] : 0;
#pragma unroll
        for (int off = 1; off < 16; off <<= 1) {
            int u = __shfl_up(ws, off, 64);
            if (t >= off) ws += u;
        }
        if (t < 16) wsum[t] = ws;
    }
    __syncthreads();
    int wid = t >> 6;
    int ex = sc - pv + ((wid > 0) ? wsum[wid - 1] : 0);
    cur[2 * t] = ex;
    cur[2 * t + 1] = ex + v0;
    __syncthreads();

    if (t < RB) {
        int row = (b << RB_SHIFT) + t;
        if (row < N_NODES) row_ptr[row] = base + cur[t << 3];  // key (t,chunk=0)
    }
    __syncthreads();
    // pass 2: counting-sort into LDS (key order), then sequential copy-out
    for (int i = t; i < cnt; i += 1024) {
        int2 e = staging[sbase + i];
        int key = ((unsigned)e.x) >> 15;
        int pos = atomicAdd(&cur[key], 1);
        sorted[pos] = make_int2(e.x & ((1 << 18) - 1), e.y);
    }
    __syncthreads();
    for (int i = t; i < cnt; i += 1024)
        edges[base + i] = sorted[i];
}

// concat(user,item) fp32 -> packed bf16 (2 per uint), fused with concat
__global__ void convert_kernel(const float4* __restrict__ u, const float4* __restrict__ it,
                               uint2* __restrict__ xh) {
    const int NU4 = USER_NUM * EMB / 4;
    const int NT4 = N_NODES * EMB / 4;
    int i = blockIdx.x * blockDim.x + threadIdx.x;
    int stride = gridDim.x * blockDim.x;
    for (; i < NT4; i += stride) {
        float4 f = (i < NU4) ? u[i] : it[i - NU4];
        xh[i] = make_uint2(pack2(f.x, f.y), pack2(f.z, f.w));
    }
}

// ---------------- phased SpMM + perturbation + mean ----------------
// Persistent: 2048 blocks (8/CU, all co-resident), 4 waves/block, RPW=19 rows
// per wave with fp32 accumulators in LDS. Edges within each row are sorted by
// column chunk (binB); phase c touches only x-rows in chunk c (4 MB = one
// XCD L2), so all waves device-wide gather from the same L2-resident window.
// No grid barrier: rows are wave-private, so phasing is locality-only --
// blocks start together and drift stays small; worst case degrades to the
// old random-gather behavior, never to wrong results.
// mode 0: out = v ; mode 1: out += v ; mode 2: out = (out+v)/3
__global__ __launch_bounds__(256, 8) void spmm_layer_kernel(const uint* __restrict__ x,
                                                            uint* __restrict__ x_out,
                                                            const int* __restrict__ row_ptr,
                                                            const int2* __restrict__ edges,
                                                            const float* __restrict__ noise_k,
                                                            float* __restrict__ out, int mode) {
    __shared__ float accs[4][RPW * 64];                 // 19 KB
    __shared__ unsigned short st[4][RPW][6];            // 0.9 KB
    int lane = threadIdx.x & 63;
    int wv = threadIdx.x >> 6;
    int wid = blockIdx.x * 4 + wv;
    int r0 = wid * RPW;
    if (r0 >= N_NODES) return;
    int nr = min(RPW, N_NODES - r0);
    int g = lane >> 3;        // edge group 0..7
    int sub = lane & 7;       // dim slice: dims [sub*8, sub*8+8)

    float* ac = accs[wv];
    for (int k = lane; k < RPW * 64; k += 64) ac[k] = 0.f;

    // precompute per-row chunk segment boundaries (edges sorted by chunk)
    for (int j = 0; j < nr; ++j) {
        int r = r0 + j;
        int beg = row_ptr[r], endd = row_ptr[r + 1];
        int deg = endd - beg;
        int c1 = 0, c2 = 0, c3 = 0, c4 = 0;
        if (deg > 0 && deg <= 64) {
            int2 e = edges[beg + min(lane, deg - 1)];
            int ch = e.x >> CSHIFT;
            bool val = lane < deg;
            c1 = __popcll(__ballot(val && ch < 1));
            c2 = __popcll(__ballot(val && ch < 2));
            c3 = __popcll(__ballot(val && ch < 3));
            c4 = __popcll(__ballot(val && ch < 4));
        } else if (deg > 64) {                          // rare (P ~ 1e-7/row)
            for (int w = beg; w < endd; w += 64) {
                int rem = endd - w;
                int2 e = edges[w + min(lane, rem - 1)];
                int ch = e.x >> CSHIFT;
                bool val = lane < rem;
                c1 += __popcll(__ballot(val && ch < 1));
                c2 += __popcll(__ballot(val && ch < 2));
                c3 += __popcll(__ballot(val && ch < 3));
                c4 += __popcll(__ballot(val && ch < 4));
            }
        }
        if (lane == 0) {
            st[wv][j][0] = 0;
            st[wv][j][1] = (unsigned short)c1;
            st[wv][j][2] = (unsigned short)c2;
            st[wv][j][3] = (unsigned short)c3;
            st[wv][j][4] = (unsigned short)c4;
            st[wv][j][5] = (unsigned short)deg;
        }
    }

    // phased accumulation
    for (int c = 0; c < NCHUNK; ++c) {
        for (int j = 0; j < nr; ++j) {
            int lo16 = st[wv][j][c], hi16 = st[wv][j][c + 1];
            if (lo16 >= hi16) continue;
            int r = r0 + j;
            int beg = row_ptr[r];
            int lo = beg + lo16, hi = beg + hi16, lim = hi - 1;

            float a0 = 0.f, a1 = 0.f, a2 = 0.f, a3 = 0.f;
            float a4 = 0.f, a5 = 0.f, a6 = 0.f, a7 = 0.f;
            for (int bb = lo; bb < hi; bb += 16) {
                int i0 = bb + g, i1 = bb + 8 + g;
                int2 e0 = edges[min(i0, lim)];
                int2 e1 = edges[min(i1, lim)];
                const uint4* q0 = (const uint4*)(x + (ull)(uint)e0.x * (EMB / 2));
                const uint4* q1 = (const uint4*)(x + (ull)(uint)e1.x * (EMB / 2));
                uint4 h0 = q0[sub];
                uint4 h1 = q1[sub];
                float w0 = (i0 < hi) ? __int_as_float(e0.y) : 0.f;
                float w1 = (i1 < hi) ? __int_as_float(e1.y) : 0.f;
                a0 += w0 * bflo(h0.x); a1 += w0 * bfhi(h0.x);
                a2 += w0 * bflo(h0.y); a3 += w0 * bfhi(h0.y);
                a4 += w0 * bflo(h0.z); a5 += w0 * bfhi(h0.z);
                a6 += w0 * bflo(h0.w); a7 += w0 * bfhi(h0.w);
                a0 += w1 * bflo(h1.x); a1 += w1 * bfhi(h1.x);
                a2 += w1 * bflo(h1.y); a3 += w1 * bfhi(h1.y);
                a4 += w1 * bflo(h1.z); a5 += w1 * bfhi(h1.z);
                a6 += w1 * bflo(h1.w); a7 += w1 * bfhi(h1.w);
            }
            // fold the 8 edge-groups
#pragma unroll
            for (int off = 8; off <= 32; off <<= 1) {
                a0 += __shfl_xor(a0, off, 64); a1 += __shfl_xor(a1, off, 64);
                a2 += __shfl_xor(a2, off, 64); a3 += __shfl_xor(a3, off, 64);
                a4 += __shfl_xor(a4, off, 64); a5 += __shfl_xor(a5, off, 64);
                a6 += __shfl_xor(a6, off, 64); a7 += __shfl_xor(a7, off, 64);
            }
            if (g == 0) {                        // 8 lanes, disjoint dims
                float* ap = ac + j * 64 + sub * 8;
                ap[0] += a0; ap[1] += a1; ap[2] += a2; ap[3] += a3;
                ap[4] += a4; ap[5] += a5; ap[6] += a6; ap[7] += a7;
            }
        }
    }

    // finalize: perturbation + output (lane d owns dim d)
    for (int j = 0; j < nr; ++j) {
        int r = r0 + j;
        float a = ac[j * 64 + lane];
        float nv = noise_k[(ull)r * EMB + lane];
        float ss = nv * nv;
        ss += __shfl_xor(ss, 1, 64);
        ss += __shfl_xor(ss, 2, 64);
        ss += __shfl_xor(ss, 4, 64);
        ss += __shfl_xor(ss, 8, 64);
        ss += __shfl_xor(ss, 16, 64);
        ss += __shfl_xor(ss, 32, 64);
        float s = EPS_F / fmaxf(sqrtf(ss), NORM_EPS_F);
        float sg = (a > 0.f) ? 1.f : ((a < 0.f) ? -1.f : 0.f);
        float v = a + sg * nv * s;
        ull o = (ull)r * EMB + lane;
        if (mode == 0) out[o] = v;
        else if (mode == 1) out[o] += v;
        else out[o] = (out[o] + v) * (1.f / 3.f);
        if (mode != 2) {
            float v2 = __shfl_xor(v, 1, 64);
            if (!(lane & 1))
                x_out[(ull)r * (EMB / 2) + (lane >> 1)] = pack2(v, v2);
        }
    }
}

// ---------------- launch ----------------

extern "C" void kernel_launch(void* const* d_in, const int* in_sizes, int n_in,
                              void* d_out, int out_size, void* d_ws, size_t ws_size,
                              hipStream_t stream) {
    const float* user_emb = (const float*)d_in[0];
    const float* item_emb = (const float*)d_in[1];
    const int*   adj_rows = (const int*)d_in[2];
    const int*   adj_cols = (const int*)d_in[3];
    const float* adj_vals = (const float*)d_in[4];
    const float* noise    = (const float*)d_in[5];
    float* out = (float*)d_out;

    char* ws = (char*)d_ws;
    size_t off = 0;
    auto alloc = [&](size_t bytes) {
        char* p = ws + off;
        off += (bytes + 15) & ~size_t(15);
        return p;
    };
    int*   row_ptr     = (int*)alloc((N_NODES + 1) * sizeof(int));
    int*   gcursor     = (int*)alloc(NB * sizeof(int));
    int*   bucket_base = (int*)alloc(NB * sizeof(int));
    int2*  edges       = (int2*)alloc((size_t)NNZ * sizeof(int2));
    int2*  staging     = (int2*)alloc((size_t)NB * CAP * sizeof(int2));  // 43.2 MB
    // bf16 x buffers alias staging (staging dead after binB; xh_a written by
    // convert_kernel which runs after binB; xh_b first written by layer 0).
    uint* xh_a = (uint*)staging;                                   // 19.2 MB
    uint* xh_b = (uint*)((char*)staging + (size_t)N_NODES * EMB * 2);

    // ---- CSR build ----
    init_gcursor<<<3, 256, 0, stream>>>(gcursor);
    binA_kernel<<<BINA_GRID, 1024, 0, stream>>>(adj_rows, adj_cols, adj_vals,
                                                gcursor, staging);
    bscan_kernel<<<1, 1024, 0, stream>>>(gcursor, bucket_base, row_ptr);
    binB_kernel<<<NB, 1024, 0, stream>>>(gcursor, bucket_base, staging, edges, row_ptr);

    // ---- fp32 -> bf16 convert (fused concat) ----
    convert_kernel<<<2048, 256, 0, stream>>>((const float4*)user_emb,
                                             (const float4*)item_emb, (uint2*)xh_a);

    // ---- 3 layers ----
    const size_t NE = (size_t)N_NODES * EMB;
    spmm_layer_kernel<<<SPMM_BLOCKS, 256, 0, stream>>>(xh_a, xh_b, row_ptr, edges,
                                                       noise + 0 * NE, out, 0);
    spmm_layer_kernel<<<SPMM_BLOCKS, 256, 0, stream>>>(xh_b, xh_a, row_ptr, edges,
                                                       noise + 1 * NE, out, 1);
    spmm_layer_kernel<<<SPMM_BLOCKS, 256, 0, stream>>>(xh_a, nullptr, row_ptr, edges,
                                                       noise + 2 * NE, out, 2);
}